// Round 5
// baseline (101.933 us; speedup 1.0000x reference)
//
#include <hip/hip_runtime.h>

#define N_TOT 4096
#define N_HALF 2048
#define DIMS 64
#define BATCH 4
#define JT_PER_BATCH 1056   // sum_{ib=0}^{31} (64 - 2*ib) tiles of 128x64

typedef __attribute__((ext_vector_type(8))) short short8;
typedef __attribute__((ext_vector_type(4))) float f32x4;

#if __has_builtin(__builtin_amdgcn_exp2f)
#define EXP2F(x) __builtin_amdgcn_exp2f(x)
#else
#define EXP2F(x) exp2f(x)
#endif
#if __has_builtin(__builtin_amdgcn_sqrtf)
#define SQRTF(x) __builtin_amdgcn_sqrtf(x)
#else
#define SQRTF(x) sqrtf(x)
#endif

__device__ __forceinline__ unsigned short f2bf_rne(float f) {
    unsigned int u = __float_as_uint(f);
    unsigned int r = (u + 0x7FFFu + ((u >> 16) & 1u)) >> 16;
    return (unsigned short)r;
}
__device__ __forceinline__ float bf2f(unsigned short h) {
    return __uint_as_float(((unsigned int)h) << 16);
}

// Prep: fp32 -> bf16 hi/lo split, row sq-norms, PER-BLOCK partials for
// Ssq and colsum (no global atomics — round-4's fused atomics cost ~10us).
// 1024 blocks x 256 thr x 4 floats; 16 rows per block, single batch-half.
__global__ __launch_bounds__(256) void prep_kernel(const float* __restrict__ x,
                                                   const float* __restrict__ y,
                                                   unsigned short* __restrict__ hi,
                                                   unsigned short* __restrict__ lo,
                                                   float* __restrict__ sq,
                                                   float* __restrict__ ssq_part,
                                                   float* __restrict__ colsum_part) {
    int g = blockIdx.x;
    int t = threadIdx.x;
    bool isx = g < 512;
    int gg = isx ? g : g - 512;
    int e = (gg << 10) + (t << 2);   // flat float index within x or y
    int b = e >> 17;                 // 2048*64 floats per batch-half
    int rem = e & 131071;
    const float* src = (isx ? x : y) + e;
    size_t dst = (size_t)b * 262144 + (isx ? 0 : 131072) + rem;

    float4 v = *(const float4*)src;
    ushort4 h, l;
    h.x = f2bf_rne(v.x); l.x = f2bf_rne(v.x - bf2f(h.x));
    h.y = f2bf_rne(v.y); l.y = f2bf_rne(v.y - bf2f(h.y));
    h.z = f2bf_rne(v.z); l.z = f2bf_rne(v.z - bf2f(h.z));
    h.w = f2bf_rne(v.w); l.w = f2bf_rne(v.w - bf2f(h.w));
    *(ushort4*)(hi + dst) = h;
    *(ushort4*)(lo + dst) = l;

    // row squared norms (16 consecutive lanes own one row)
    float p = fmaf(v.x, v.x, fmaf(v.y, v.y, fmaf(v.z, v.z, v.w * v.w)));
    p += __shfl_xor(p, 1);
    p += __shfl_xor(p, 2);
    p += __shfl_xor(p, 4);
    p += __shfl_xor(p, 8);
    int rwi = rem >> 6;
    if ((t & 15) == 0)
        sq[b * N_TOT + (isx ? rwi : N_HALF + rwi)] = p;

    // block partial of sum(sq): xor16/xor32 add the wave's 4 distinct rows once
    float q = p;
    q += __shfl_xor(q, 16);
    q += __shfl_xor(q, 32);
    __shared__ float wsum[4];
    int wid = t >> 6;
    if ((t & 63) == 0) wsum[wid] = q;

    // column partials: lanes t, t^16, t^32, t^48 share the same 4 columns
    float4 c = v;
    c.x += __shfl_xor(c.x, 16); c.y += __shfl_xor(c.y, 16);
    c.z += __shfl_xor(c.z, 16); c.w += __shfl_xor(c.w, 16);
    c.x += __shfl_xor(c.x, 32); c.y += __shfl_xor(c.y, 32);
    c.z += __shfl_xor(c.z, 32); c.w += __shfl_xor(c.w, 32);
    __shared__ float4 csh[4][16];
    if ((t & 63) < 16) csh[wid][t & 63] = c;
    __syncthreads();
    if (t == 0) ssq_part[g] = wsum[0] + wsum[1] + wsum[2] + wsum[3];
    if (t < 16) {
        float4 s0 = csh[0][t], s1 = csh[1][t], s2 = csh[2][t], s3 = csh[3][t];
        float4 o;
        o.x = s0.x + s1.x + s2.x + s3.x;
        o.y = s0.y + s1.y + s2.y + s3.y;
        o.z = s0.z + s1.z + s2.z + s3.z;
        o.w = s0.w + s1.w + s2.w + s3.w;
        *(float4*)(colsum_part + (size_t)g * 64 + t * 4) = o;
    }
}

// Reduce partials -> k0[b] = -log2(e)/bw. 1 block, wave w handles batch w.
__global__ void bw_kernel(const float* __restrict__ ssq_part,
                          const float* __restrict__ colsum_part,
                          float* __restrict__ k0arr) {
    int t = threadIdx.x;
    int b = t >> 6, c = t & 63;
    // column sum for (b, c): 128 x-blocks + 128 y-blocks
    float cs = 0.f;
    for (int p = 0; p < 128; ++p) {
        cs += colsum_part[(size_t)(128 * b + p) * 64 + c];
        cs += colsum_part[(size_t)(512 + 128 * b + p) * 64 + c];
    }
    double cc = (double)cs * (double)cs;
#pragma unroll
    for (int o = 32; o > 0; o >>= 1) cc += __shfl_xor(cc, o);  // s2 over 64 cols

    float sp = 0.f;
#pragma unroll
    for (int q = 0; q < 4; ++q) {
        int pp = c + 64 * q;
        int g = (pp < 128) ? (128 * b + pp) : (512 + 128 * b + (pp - 128));
        sp += ssq_part[g];
    }
    double sd = (double)sp;
#pragma unroll
    for (int o = 32; o > 0; o >>= 1) sd += __shfl_xor(sd, o);  // Ssq for batch

    if (c == 0) {
        double sumL2 = 2.0 * (double)N_TOT * sd - 2.0 * cc;
        double bw = sumL2 / ((double)N_TOT * (double)N_TOT - (double)N_TOT);
        bw *= 0.25;  // / KERNEL_MUL^(KERNEL_NUM//2)
        k0arr[b] = (float)(-1.4426950408889634 / bw);
    }
}

// Main: 128x64 blocks, 4 waves of 64x32 (low reg footprint -> 4 waves/SIMD),
// split-bf16 3-pass MFMA, sqrt-chain exp epilogue, wave-uniform weights.
__global__ __launch_bounds__(256, 4) void mmd_mfma(const unsigned short* __restrict__ hi,
                                                   const unsigned short* __restrict__ lo,
                                                   const float* __restrict__ sq,
                                                   const float* __restrict__ k0arr,
                                                   double* __restrict__ loss) {
    int wg = blockIdx.x;
    int b = wg / JT_PER_BATCH;
    int r = wg % JT_PER_BATCH;
    int ib = 0, cum = 0;
    while (r >= cum + (64 - 2 * ib)) { cum += 64 - 2 * ib; ++ib; }
    int jb = 2 * ib + (r - cum);

    int wid = threadIdx.x >> 6, lane = threadIdx.x & 63;
    int i0 = ib * 128 + (wid >> 1) * 64;   // 64 rows
    int j0 = jb * 64 + (wid & 1) * 32;     // 32 cols

    double acc_d = 0.0;
    if (i0 < j0 + 32) {  // else: wave entirely below diagonal -> w=0
        bool mixed = (j0 < i0 + 64);  // diagonal crosses this wave tile
        float wsign = ((i0 < N_HALF) == (j0 < N_HALF)) ? 1.f : -1.f;
        float k0 = k0arr[b];
        const unsigned short* Hb = hi + (size_t)b * 262144;
        const unsigned short* Lb = lo + (size_t)b * 262144;
        int lrow = lane & 15;
        int kbase = (lane >> 4) * 8;

        f32x4 acc[4][2];
#pragma unroll
        for (int mf = 0; mf < 4; ++mf)
#pragma unroll
            for (int nf = 0; nf < 2; ++nf)
                acc[mf][nf] = (f32x4){0.f, 0.f, 0.f, 0.f};

#pragma unroll 1
        for (int ks = 0; ks < 2; ++ks) {
            int ko = ks * 32 + kbase;
            short8 ah[4], al[4], bh[2], bl[2];
#pragma unroll
            for (int f = 0; f < 4; ++f) {
                size_t ra = (size_t)(i0 + f * 16 + lrow) * DIMS + ko;
                ah[f] = *(const short8*)(Hb + ra);
                al[f] = *(const short8*)(Lb + ra);
            }
#pragma unroll
            for (int n = 0; n < 2; ++n) {
                size_t rb = (size_t)(j0 + n * 16 + lrow) * DIMS + ko;
                bh[n] = *(const short8*)(Hb + rb);
                bl[n] = *(const short8*)(Lb + rb);
            }
#pragma unroll
            for (int mf = 0; mf < 4; ++mf)
#pragma unroll
                for (int nf = 0; nf < 2; ++nf) {
                    acc[mf][nf] = __builtin_amdgcn_mfma_f32_16x16x32_bf16(ah[mf], bh[nf], acc[mf][nf], 0, 0, 0);
                    acc[mf][nf] = __builtin_amdgcn_mfma_f32_16x16x32_bf16(ah[mf], bl[nf], acc[mf][nf], 0, 0, 0);
                    acc[mf][nf] = __builtin_amdgcn_mfma_f32_16x16x32_bf16(al[mf], bh[nf], acc[mf][nf], 0, 0, 0);
                }
        }

        const float* sqb = sq + b * N_TOT;
        int rquad = (lane >> 4) * 4;  // C layout: row = (lane>>4)*4 + reg
        float m2k0 = -2.f * k0;
        float k0j0 = k0 * sqb[j0 + lrow];
        float k0j1 = k0 * sqb[j0 + 16 + lrow];
        float eacc = 0.f;
#pragma unroll
        for (int mf = 0; mf < 4; ++mf) {
            float4 sv = *(const float4*)(sqb + i0 + mf * 16 + rquad);
            float k0i[4] = {k0 * sv.x, k0 * sv.y, k0 * sv.z, k0 * sv.w};
#pragma unroll
            for (int nf = 0; nf < 2; ++nf) {
                float k0j = nf ? k0j1 : k0j0;
#pragma unroll
                for (int rg = 0; rg < 4; ++rg) {
                    float tt = fmaf(m2k0, acc[mf][nf][rg], k0i[rg] + k0j);
                    float e0 = EXP2F(tt);
                    float e1 = SQRTF(e0);
                    float e2 = SQRTF(e1);
                    float e3 = SQRTF(e2);
                    float e4 = SQRTF(e3);
                    float es = ((e0 + e1) + (e2 + e3)) + e4;
                    if (mixed) {
                        int i = i0 + mf * 16 + rquad + rg;
                        int j = j0 + nf * 16 + lrow;
                        float w = (j > i) ? 2.f : ((j == i) ? 1.f : 0.f);
                        eacc = fmaf(w, es, eacc);
                    } else {
                        eacc += es;  // fully above diagonal: w = 2 (folded below)
                    }
                }
            }
        }
        float scale = mixed ? wsign : 2.f * wsign;
        acc_d = (double)(eacc * scale);
    }

#pragma unroll
    for (int o = 32; o > 0; o >>= 1) acc_d += __shfl_down(acc_d, o);
    __shared__ double wred[4];
    if ((threadIdx.x & 63) == 0) wred[threadIdx.x >> 6] = acc_d;
    __syncthreads();
    if (threadIdx.x == 0)
        atomicAdd(loss + b, wred[0] + wred[1] + wred[2] + wred[3]);
}

__global__ void finalize_kernel(const double* __restrict__ loss,
                                float* __restrict__ out) {
    int t = threadIdx.x;
    if (t < BATCH)
        out[t] = (float)(loss[t] / ((double)N_HALF * (double)N_HALF));
}

extern "C" void kernel_launch(void* const* d_in, const int* in_sizes, int n_in,
                              void* d_out, int out_size, void* d_ws, size_t ws_size,
                              hipStream_t stream) {
    const float* x = (const float*)d_in[0];
    const float* y = (const float*)d_in[1];
    float* out = (float*)d_out;
    char* ws = (char*)d_ws;

    double* loss        = (double*)ws;                    // [0, 32)
    float*  k0arr       = (float*)(ws + 64);              // [64, 80)
    float*  ssq_part    = (float*)(ws + 4096);            // 4 KB
    float*  colsum_part = (float*)(ws + 8192);            // 256 KB
    float*  sq          = (float*)(ws + 270336);          // 64 KB
    unsigned short* tot_hi = (unsigned short*)(ws + 335872);            // 2 MB
    unsigned short* tot_lo = (unsigned short*)(ws + 335872 + 2097152);  // 2 MB

    hipMemsetAsync(ws, 0, 96, stream);  // zero loss accumulators

    prep_kernel<<<1024, 256, 0, stream>>>(x, y, tot_hi, tot_lo, sq, ssq_part, colsum_part);
    bw_kernel<<<1, 256, 0, stream>>>(ssq_part, colsum_part, k0arr);
    mmd_mfma<<<BATCH * JT_PER_BATCH, 256, 0, stream>>>(tot_hi, tot_lo, sq, k0arr, loss);
    finalize_kernel<<<1, 64, 0, stream>>>(loss, out);
}

// Round 6
// 90.062 us; speedup vs baseline: 1.1318x; 1.1318x over previous
//
#include <hip/hip_runtime.h>

#define N_TOT 4096
#define N_HALF 2048
#define DIMS 64
#define BATCH 4
#define TGRID 32             // 4096/128 tile rows
#define PAIRS_PER_BATCH 528  // 32*33/2 triangular 128x128 tiles
#define NWG (BATCH * PAIRS_PER_BATCH)  // 2112, divisible by 8

typedef __attribute__((ext_vector_type(8))) short short8;
typedef __attribute__((ext_vector_type(4))) float f32x4;

#if __has_builtin(__builtin_amdgcn_exp2f)
#define EXP2F(x) __builtin_amdgcn_exp2f(x)
#else
#define EXP2F(x) exp2f(x)
#endif

__device__ __forceinline__ unsigned short f2bf_rne(float f) {
    unsigned int u = __float_as_uint(f);
    unsigned int r = (u + 0x7FFFu + ((u >> 16) & 1u)) >> 16;
    return (unsigned short)r;
}
__device__ __forceinline__ float bf2f(unsigned short h) {
    return __uint_as_float(((unsigned int)h) << 16);
}

// Prep: fp32 -> bf16 hi/lo split, row sq-norms, per-block partials for Ssq and
// colsum. 256 blocks x 256 thr x 16 floats (4 x float4, 1024-float stride).
__global__ __launch_bounds__(256) void prep_kernel(const float* __restrict__ x,
                                                   const float* __restrict__ y,
                                                   unsigned short* __restrict__ hi,
                                                   unsigned short* __restrict__ lo,
                                                   float* __restrict__ sq,
                                                   float* __restrict__ ssq_part,
                                                   float* __restrict__ colsum_part) {
    int g = blockIdx.x;
    int t = threadIdx.x;
    bool isx = g < 128;
    int gg = isx ? g : g - 128;
    int base = gg << 12;             // 4096 floats per block
    int b = gg >> 5;                 // 32 blocks per batch-half
    const float* src = isx ? x : y;

    float q_acc = 0.f;
    float4 c_acc = {0.f, 0.f, 0.f, 0.f};
#pragma unroll
    for (int it = 0; it < 4; ++it) {
        int e = base + (it << 10) + (t << 2);
        int rem = e & 131071;
        float4 v = *(const float4*)(src + e);
        size_t dst = (size_t)b * 262144 + (isx ? 0 : 131072) + rem;
        ushort4 h, l;
        h.x = f2bf_rne(v.x); l.x = f2bf_rne(v.x - bf2f(h.x));
        h.y = f2bf_rne(v.y); l.y = f2bf_rne(v.y - bf2f(h.y));
        h.z = f2bf_rne(v.z); l.z = f2bf_rne(v.z - bf2f(h.z));
        h.w = f2bf_rne(v.w); l.w = f2bf_rne(v.w - bf2f(h.w));
        *(ushort4*)(hi + dst) = h;
        *(ushort4*)(lo + dst) = l;

        // row squared norm: 16 consecutive lanes cover one 64-float row
        float p = fmaf(v.x, v.x, fmaf(v.y, v.y, fmaf(v.z, v.z, v.w * v.w)));
        p += __shfl_xor(p, 1);
        p += __shfl_xor(p, 2);
        p += __shfl_xor(p, 4);
        p += __shfl_xor(p, 8);
        int rwi = rem >> 6;
        if ((t & 15) == 0)
            sq[b * N_TOT + (isx ? rwi : N_HALF + rwi)] = p;

        // wave partial of sum(sq): xor16/xor32 add the wave's 4 distinct rows once
        float q = p;
        q += __shfl_xor(q, 16);
        q += __shfl_xor(q, 32);
        q_acc += q;

        // column partials: lanes t, t^16, t^32, t^48 share the same 4 columns
        float4 c = v;
        c.x += __shfl_xor(c.x, 16); c.y += __shfl_xor(c.y, 16);
        c.z += __shfl_xor(c.z, 16); c.w += __shfl_xor(c.w, 16);
        c.x += __shfl_xor(c.x, 32); c.y += __shfl_xor(c.y, 32);
        c.z += __shfl_xor(c.z, 32); c.w += __shfl_xor(c.w, 32);
        c_acc.x += c.x; c_acc.y += c.y; c_acc.z += c.z; c_acc.w += c.w;
    }

    __shared__ float wsum[4];
    __shared__ float4 csh[4][16];
    int wid = t >> 6;
    if ((t & 63) == 0) wsum[wid] = q_acc;
    if ((t & 63) < 16) csh[wid][t & 63] = c_acc;
    __syncthreads();
    if (t == 0) ssq_part[g] = wsum[0] + wsum[1] + wsum[2] + wsum[3];
    if (t < 16) {
        float4 s0 = csh[0][t], s1 = csh[1][t], s2 = csh[2][t], s3 = csh[3][t];
        float4 o;
        o.x = s0.x + s1.x + s2.x + s3.x;
        o.y = s0.y + s1.y + s2.y + s3.y;
        o.z = s0.z + s1.z + s2.z + s3.z;
        o.w = s0.w + s1.w + s2.w + s3.w;
        *(float4*)(colsum_part + (size_t)g * 64 + t * 4) = o;
    }
}

// Reduce partials -> k0[b] = -log2(e)/bw. 1 block; wave b handles batch b.
// Each batch has 64 partial blocks (32 x + 32 y) <-> 64 lanes.
__global__ void bw_kernel(const float* __restrict__ ssq_part,
                          const float* __restrict__ colsum_part,
                          float* __restrict__ k0arr) {
    int t = threadIdx.x;
    int b = t >> 6, c = t & 63;
    int g_c = (c < 32) ? (b * 32 + c) : (128 + b * 32 + (c - 32));

    // Ssq: lane c owns partial block g_c
    double sd = (double)ssq_part[g_c];
#pragma unroll
    for (int o = 32; o > 0; o >>= 1) sd += __shfl_xor(sd, o);

    // colsum for column c: sum over the batch's 64 partial blocks
    float cs = 0.f;
#pragma unroll 8
    for (int p = 0; p < 32; ++p) {
        cs += colsum_part[(size_t)(b * 32 + p) * 64 + c];
        cs += colsum_part[(size_t)(128 + b * 32 + p) * 64 + c];
    }
    double cc = (double)cs * (double)cs;
#pragma unroll
    for (int o = 32; o > 0; o >>= 1) cc += __shfl_xor(cc, o);

    if (c == 0) {
        double sumL2 = 2.0 * (double)N_TOT * sd - 2.0 * cc;
        double bw = sumL2 / ((double)N_TOT * (double)N_TOT - (double)N_TOT);
        bw *= 0.25;  // / KERNEL_MUL^(KERNEL_NUM//2)
        k0arr[b] = (float)(-1.4426950408889634 / bw);
    }
}

// Main: 128x128 blocks (triangular), 4 waves of 64x64, split-bf16 3-pass MFMA.
// Epilogue: 1 exp2 + 4 squarings (exp2(t/16) chain) instead of 5 trans ops.
__global__ __launch_bounds__(256, 3) void mmd_mfma(const unsigned short* __restrict__ hi,
                                                   const unsigned short* __restrict__ lo,
                                                   const float* __restrict__ sq,
                                                   const float* __restrict__ k0arr,
                                                   double* __restrict__ loss) {
    // bijective XCD swizzle (NWG % 8 == 0): consecutive same-XCD blocks get
    // consecutive tiles -> A-panel reuse lands in the same per-XCD L2.
    int wg0 = blockIdx.x;
    int wg = (wg0 & 7) * (NWG / 8) + (wg0 >> 3);
    int b = wg / PAIRS_PER_BATCH;
    int r = wg % PAIRS_PER_BATCH;
    int ib = 0, cum = 0;
    while (r >= cum + (TGRID - ib)) { cum += TGRID - ib; ++ib; }
    int jb = ib + (r - cum);

    int wid = threadIdx.x >> 6, lane = threadIdx.x & 63;
    int i_base = ib * 128 + (wid >> 1) * 64;
    int j_base = jb * 128 + (wid & 1) * 64;

    bool skip = (i_base > j_base);
    bool diag = (i_base == j_base);
    float wsign = ((i_base < N_HALF) == (j_base < N_HALF)) ? 1.f : -1.f;

    double acc_d = 0.0;
    if (!skip) {
        // k16 = k0/16 folded into all epilogue terms (uniform scalar load)
        float k16 = k0arr[b] * 0.0625f;
        const float* sqb = sq + b * N_TOT;
        int lrow = lane & 15;
        int rquad = (lane >> 4) * 4;

        // preload sq terms BEFORE the MFMA phase (latency hidden under MFMA)
        float ki16[4][4], kj16[4];
#pragma unroll
        for (int mf = 0; mf < 4; ++mf) {
            float4 sv = *(const float4*)(sqb + i_base + mf * 16 + rquad);
            ki16[mf][0] = k16 * sv.x; ki16[mf][1] = k16 * sv.y;
            ki16[mf][2] = k16 * sv.z; ki16[mf][3] = k16 * sv.w;
        }
#pragma unroll
        for (int nf = 0; nf < 4; ++nf)
            kj16[nf] = k16 * sqb[j_base + nf * 16 + lrow];

        const unsigned short* Hb = hi + (size_t)b * 262144;
        const unsigned short* Lb = lo + (size_t)b * 262144;
        int kbase = (lane >> 4) * 8;

        f32x4 acc[4][4];
#pragma unroll
        for (int mf = 0; mf < 4; ++mf)
#pragma unroll
            for (int nf = 0; nf < 4; ++nf)
                acc[mf][nf] = (f32x4){0.f, 0.f, 0.f, 0.f};

#pragma unroll
        for (int ks = 0; ks < 2; ++ks) {
            int ko = ks * 32 + kbase;
            short8 ah[4], al[4], bh[4], bl[4];
#pragma unroll
            for (int f = 0; f < 4; ++f) {
                size_t ra = (size_t)(i_base + f * 16 + lrow) * DIMS + ko;
                size_t rb = (size_t)(j_base + f * 16 + lrow) * DIMS + ko;
                ah[f] = *(const short8*)(Hb + ra);
                al[f] = *(const short8*)(Lb + ra);
                bh[f] = *(const short8*)(Hb + rb);
                bl[f] = *(const short8*)(Lb + rb);
            }
#pragma unroll
            for (int mf = 0; mf < 4; ++mf)
#pragma unroll
                for (int nf = 0; nf < 4; ++nf) {
                    acc[mf][nf] = __builtin_amdgcn_mfma_f32_16x16x32_bf16(ah[mf], bh[nf], acc[mf][nf], 0, 0, 0);
                    acc[mf][nf] = __builtin_amdgcn_mfma_f32_16x16x32_bf16(ah[mf], bl[nf], acc[mf][nf], 0, 0, 0);
                    acc[mf][nf] = __builtin_amdgcn_mfma_f32_16x16x32_bf16(al[mf], bh[nf], acc[mf][nf], 0, 0, 0);
                }
        }

        float m2k16 = -2.f * k16;
        float eacc = 0.f;
#pragma unroll
        for (int mf = 0; mf < 4; ++mf)
#pragma unroll
            for (int nf = 0; nf < 4; ++nf) {
#pragma unroll
                for (int rg = 0; rg < 4; ++rg) {
                    // t16 = (k0/16) * L2
                    float t16 = fmaf(m2k16, acc[mf][nf][rg], ki16[mf][rg] + kj16[nf]);
                    float e4 = EXP2F(t16);       // exp2(t/16)
                    float e3 = e4 * e4;          // exp2(t/8)
                    float e2 = e3 * e3;          // exp2(t/4)
                    float e1 = e2 * e2;          // exp2(t/2)
                    float e0 = e1 * e1;          // exp2(t)
                    float es = ((e0 + e1) + (e2 + e3)) + e4;
                    if (diag) {
                        int i = i_base + mf * 16 + rquad + rg;
                        int j = j_base + nf * 16 + lrow;
                        float w = (j > i) ? 2.f : ((j == i) ? 1.f : 0.f);
                        eacc = fmaf(w, es, eacc);
                    } else {
                        eacc += es;
                    }
                }
            }
        float scale = diag ? wsign : 2.f * wsign;
        acc_d = (double)(eacc * scale);
    }

#pragma unroll
    for (int o = 32; o > 0; o >>= 1) acc_d += __shfl_down(acc_d, o);
    __shared__ double wred[4];
    if ((threadIdx.x & 63) == 0) wred[wid] = acc_d;
    __syncthreads();
    if (threadIdx.x == 0)
        atomicAdd(loss + b, wred[0] + wred[1] + wred[2] + wred[3]);
}

__global__ void finalize_kernel(const double* __restrict__ loss,
                                float* __restrict__ out) {
    int t = threadIdx.x;
    if (t < BATCH)
        out[t] = (float)(loss[t] / ((double)N_HALF * (double)N_HALF));
}

extern "C" void kernel_launch(void* const* d_in, const int* in_sizes, int n_in,
                              void* d_out, int out_size, void* d_ws, size_t ws_size,
                              hipStream_t stream) {
    const float* x = (const float*)d_in[0];
    const float* y = (const float*)d_in[1];
    float* out = (float*)d_out;
    char* ws = (char*)d_ws;

    double* loss        = (double*)ws;                    // [0, 32)
    float*  k0arr       = (float*)(ws + 64);              // [64, 80)
    float*  ssq_part    = (float*)(ws + 4096);            // 1 KB
    float*  colsum_part = (float*)(ws + 8192);            // 64 KB
    float*  sq          = (float*)(ws + 73728);           // 64 KB
    unsigned short* tot_hi = (unsigned short*)(ws + 139264);            // 2 MB
    unsigned short* tot_lo = (unsigned short*)(ws + 139264 + 2097152);  // 2 MB

    hipMemsetAsync(ws, 0, 96, stream);  // zero loss accumulators

    prep_kernel<<<256, 256, 0, stream>>>(x, y, tot_hi, tot_lo, sq, ssq_part, colsum_part);
    bw_kernel<<<1, 256, 0, stream>>>(ssq_part, colsum_part, k0arr);
    mmd_mfma<<<NWG, 256, 0, stream>>>(tot_hi, tot_lo, sq, k0arr, loss);
    finalize_kernel<<<1, 64, 0, stream>>>(loss, out);
}

// Round 7
// 74.810 us; speedup vs baseline: 1.3626x; 1.2039x over previous
//
#include <hip/hip_runtime.h>

#define N_TOT 4096
#define N_HALF 2048
#define DIMS 64
#define BATCH 4
#define TGRID 32             // 4096/128 tile rows
#define PAIRS_PER_BATCH 528  // 32*33/2 triangular 128x128 tiles
#define NWG (BATCH * PAIRS_PER_BATCH)  // 2112, divisible by 8

typedef __attribute__((ext_vector_type(8))) short short8;
typedef __attribute__((ext_vector_type(4))) float f32x4;

#if __has_builtin(__builtin_amdgcn_exp2f)
#define EXP2F(x) __builtin_amdgcn_exp2f(x)
#else
#define EXP2F(x) exp2f(x)
#endif

__device__ __forceinline__ unsigned short f2bf_rne(float f) {
    unsigned int u = __float_as_uint(f);
    unsigned int r = (u + 0x7FFFu + ((u >> 16) & 1u)) >> 16;
    return (unsigned short)r;
}
__device__ __forceinline__ float bf2f(unsigned short h) {
    return __uint_as_float(((unsigned int)h) << 16);
}

// Prep: fp32 -> bf16 hi/lo split, row sq-norms, per-block partials for Ssq and
// colsum. 256 blocks x 256 thr x 16 floats (4 x float4, 1024-float stride).
__global__ __launch_bounds__(256) void prep_kernel(const float* __restrict__ x,
                                                   const float* __restrict__ y,
                                                   unsigned short* __restrict__ hi,
                                                   unsigned short* __restrict__ lo,
                                                   float* __restrict__ sq,
                                                   float* __restrict__ ssq_part,
                                                   float* __restrict__ colsum_part) {
    int g = blockIdx.x;
    int t = threadIdx.x;
    bool isx = g < 128;
    int gg = isx ? g : g - 128;
    int base = gg << 12;             // 4096 floats per block
    int b = gg >> 5;                 // 32 blocks per batch-half
    const float* src = isx ? x : y;

    float q_acc = 0.f;
    float4 c_acc = {0.f, 0.f, 0.f, 0.f};
#pragma unroll
    for (int it = 0; it < 4; ++it) {
        int e = base + (it << 10) + (t << 2);
        int rem = e & 131071;
        float4 v = *(const float4*)(src + e);
        size_t dst = (size_t)b * 262144 + (isx ? 0 : 131072) + rem;
        ushort4 h, l;
        h.x = f2bf_rne(v.x); l.x = f2bf_rne(v.x - bf2f(h.x));
        h.y = f2bf_rne(v.y); l.y = f2bf_rne(v.y - bf2f(h.y));
        h.z = f2bf_rne(v.z); l.z = f2bf_rne(v.z - bf2f(h.z));
        h.w = f2bf_rne(v.w); l.w = f2bf_rne(v.w - bf2f(h.w));
        *(ushort4*)(hi + dst) = h;
        *(ushort4*)(lo + dst) = l;

        // row squared norm: 16 consecutive lanes cover one 64-float row
        float p = fmaf(v.x, v.x, fmaf(v.y, v.y, fmaf(v.z, v.z, v.w * v.w)));
        p += __shfl_xor(p, 1);
        p += __shfl_xor(p, 2);
        p += __shfl_xor(p, 4);
        p += __shfl_xor(p, 8);
        int rwi = rem >> 6;
        if ((t & 15) == 0)
            sq[b * N_TOT + (isx ? rwi : N_HALF + rwi)] = p;

        // wave partial of sum(sq): xor16/xor32 add the wave's 4 distinct rows once
        float q = p;
        q += __shfl_xor(q, 16);
        q += __shfl_xor(q, 32);
        q_acc += q;

        // column partials: lanes t, t^16, t^32, t^48 share the same 4 columns
        float4 c = v;
        c.x += __shfl_xor(c.x, 16); c.y += __shfl_xor(c.y, 16);
        c.z += __shfl_xor(c.z, 16); c.w += __shfl_xor(c.w, 16);
        c.x += __shfl_xor(c.x, 32); c.y += __shfl_xor(c.y, 32);
        c.z += __shfl_xor(c.z, 32); c.w += __shfl_xor(c.w, 32);
        c_acc.x += c.x; c_acc.y += c.y; c_acc.z += c.z; c_acc.w += c.w;
    }

    __shared__ float wsum[4];
    __shared__ float4 csh[4][16];
    int wid = t >> 6;
    if ((t & 63) == 0) wsum[wid] = q_acc;
    if ((t & 63) < 16) csh[wid][t & 63] = c_acc;
    __syncthreads();
    if (t == 0) ssq_part[g] = wsum[0] + wsum[1] + wsum[2] + wsum[3];
    if (t < 16) {
        float4 s0 = csh[0][t], s1 = csh[1][t], s2 = csh[2][t], s3 = csh[3][t];
        float4 o;
        o.x = s0.x + s1.x + s2.x + s3.x;
        o.y = s0.y + s1.y + s2.y + s3.y;
        o.z = s0.z + s1.z + s2.z + s3.z;
        o.w = s0.w + s1.w + s2.w + s3.w;
        *(float4*)(colsum_part + (size_t)g * 64 + t * 4) = o;
    }
}

// Reduce partials -> k0[b] = -log2(e)/bw. 1 block; wave b handles batch b.
__global__ void bw_kernel(const float* __restrict__ ssq_part,
                          const float* __restrict__ colsum_part,
                          float* __restrict__ k0arr) {
    int t = threadIdx.x;
    int b = t >> 6, c = t & 63;
    int g_c = (c < 32) ? (b * 32 + c) : (128 + b * 32 + (c - 32));

    double sd = (double)ssq_part[g_c];
#pragma unroll
    for (int o = 32; o > 0; o >>= 1) sd += __shfl_xor(sd, o);

    float cs = 0.f;
#pragma unroll 8
    for (int p = 0; p < 32; ++p) {
        cs += colsum_part[(size_t)(b * 32 + p) * 64 + c];
        cs += colsum_part[(size_t)(128 + b * 32 + p) * 64 + c];
    }
    double cc = (double)cs * (double)cs;
#pragma unroll
    for (int o = 32; o > 0; o >>= 1) cc += __shfl_xor(cc, o);

    if (c == 0) {
        double sumL2 = 2.0 * (double)N_TOT * sd - 2.0 * cc;
        double bw = sumL2 / ((double)N_TOT * (double)N_TOT - (double)N_TOT);
        bw *= 0.25;  // / KERNEL_MUL^(KERNEL_NUM//2)
        k0arr[b] = (float)(-1.4426950408889634 / bw);
    }
}

// Main: triangular 128x128 blocks, 4 waves of 64x64, split-bf16 3-pass MFMA.
// Row-pipelined: per 16-row fragment row, {prefetch next A, MFMA, epilogue}.
// Accumulator live set = 16 regs (1 row) -> 4 waves/SIMD; epilogue VALU of
// row mf overlaps MFMA (matrix pipe) of row mf+1. No atomics: per-block store.
__global__ __launch_bounds__(256, 4) void mmd_mfma(const unsigned short* __restrict__ hi,
                                                   const unsigned short* __restrict__ lo,
                                                   const float* __restrict__ sq,
                                                   const float* __restrict__ k0arr,
                                                   double* __restrict__ pblock) {
    // bijective XCD swizzle (NWG % 8 == 0): consecutive logical tiles land on
    // the same XCD's L2 (r6: FETCH 16.7 -> 3.7 MB).
    int wg0 = blockIdx.x;
    int wg = (wg0 & 7) * (NWG / 8) + (wg0 >> 3);
    int b = wg / PAIRS_PER_BATCH;
    int r = wg % PAIRS_PER_BATCH;
    int ib = 0, cum = 0;
    while (r >= cum + (TGRID - ib)) { cum += TGRID - ib; ++ib; }
    int jb = ib + (r - cum);

    int wid = threadIdx.x >> 6, lane = threadIdx.x & 63;
    int i_base = ib * 128 + (wid >> 1) * 64;
    int j_base = jb * 128 + (wid & 1) * 64;

    bool skip = (i_base > j_base);   // strictly-lower wave of a diagonal block
    bool diag = (i_base == j_base);
    float wsign = ((i_base < N_HALF) == (j_base < N_HALF)) ? 1.f : -1.f;

    double acc_d = 0.0;
    if (!skip) {
        float k16 = k0arr[b] * 0.0625f;      // (k0/16), uniform
        const float* sqb = sq + b * N_TOT;
        int lrow = lane & 15;
        int rquad = (lane >> 4) * 4;
        int kbase = (lane >> 4) * 8;
        const unsigned short* Hb = hi + (size_t)b * 262144;
        const unsigned short* Lb = lo + (size_t)b * 262144;

        // B fragments for both k-halves (64 VGPR, live throughout)
        short8 bh[2][4], bl[2][4];
#pragma unroll
        for (int ks = 0; ks < 2; ++ks)
#pragma unroll
            for (int nf = 0; nf < 4; ++nf) {
                size_t rb = (size_t)(j_base + nf * 16 + lrow) * DIMS + ks * 32 + kbase;
                bh[ks][nf] = *(const short8*)(Hb + rb);
                bl[ks][nf] = *(const short8*)(Lb + rb);
            }
        float kj16[4];
#pragma unroll
        for (int nf = 0; nf < 4; ++nf)
            kj16[nf] = k16 * sqb[j_base + nf * 16 + lrow];
        float m2k16 = -2.f * k16;

        // A row 0 + its sq
        short8 ahc[2], alc[2];
#pragma unroll
        for (int ks = 0; ks < 2; ++ks) {
            size_t ra = (size_t)(i_base + lrow) * DIMS + ks * 32 + kbase;
            ahc[ks] = *(const short8*)(Hb + ra);
            alc[ks] = *(const short8*)(Lb + ra);
        }
        float4 svc = *(const float4*)(sqb + i_base + rquad);

        float eacc = 0.f;
#pragma unroll
        for (int mf = 0; mf < 4; ++mf) {
            // prefetch next A row (latency hides under this row's MFMA+epilogue)
            short8 ahn[2], aln[2];
            float4 svn;
            if (mf < 3) {
#pragma unroll
                for (int ks = 0; ks < 2; ++ks) {
                    size_t ra = (size_t)(i_base + (mf + 1) * 16 + lrow) * DIMS + ks * 32 + kbase;
                    ahn[ks] = *(const short8*)(Hb + ra);
                    aln[ks] = *(const short8*)(Lb + ra);
                }
                svn = *(const float4*)(sqb + i_base + (mf + 1) * 16 + rquad);
            }

            f32x4 accr[4];
#pragma unroll
            for (int nf = 0; nf < 4; ++nf) accr[nf] = (f32x4){0.f, 0.f, 0.f, 0.f};
#pragma unroll
            for (int ks = 0; ks < 2; ++ks)
#pragma unroll
                for (int nf = 0; nf < 4; ++nf) {
                    accr[nf] = __builtin_amdgcn_mfma_f32_16x16x32_bf16(ahc[ks], bh[ks][nf], accr[nf], 0, 0, 0);
                    accr[nf] = __builtin_amdgcn_mfma_f32_16x16x32_bf16(ahc[ks], bl[ks][nf], accr[nf], 0, 0, 0);
                    accr[nf] = __builtin_amdgcn_mfma_f32_16x16x32_bf16(alc[ks], bh[ks][nf], accr[nf], 0, 0, 0);
                }

            float ki16[4] = {k16 * svc.x, k16 * svc.y, k16 * svc.z, k16 * svc.w};
#pragma unroll
            for (int nf = 0; nf < 4; ++nf) {
#pragma unroll
                for (int rg = 0; rg < 4; ++rg) {
                    float t16 = fmaf(m2k16, accr[nf][rg], ki16[rg] + kj16[nf]);
                    float e4 = EXP2F(t16);       // exp2(t/16)
                    float e3 = e4 * e4;          // ^2 chain replaces sqrt chain
                    float e2 = e3 * e3;
                    float e1 = e2 * e2;
                    float e0 = e1 * e1;
                    float es = ((e0 + e1) + (e2 + e3)) + e4;
                    if (diag) {
                        int i = i_base + mf * 16 + rquad + rg;
                        int j = j_base + nf * 16 + lrow;
                        float w = (j > i) ? 2.f : ((j == i) ? 1.f : 0.f);
                        eacc = fmaf(w, es, eacc);
                    } else {
                        eacc += es;
                    }
                }
            }

            if (mf < 3) {
                ahc[0] = ahn[0]; ahc[1] = ahn[1];
                alc[0] = aln[0]; alc[1] = aln[1];
                svc = svn;
            }
        }
        acc_d = (double)(eacc * (diag ? wsign : 2.f * wsign));
    }

#pragma unroll
    for (int o = 32; o > 0; o >>= 1) acc_d += __shfl_down(acc_d, o);
    __shared__ double wred[4];
    if ((threadIdx.x & 63) == 0) wred[wid] = acc_d;
    __syncthreads();
    if (threadIdx.x == 0)
        pblock[wg] = wred[0] + wred[1] + wred[2] + wred[3];
}

// Final reduce: block b sums its batch's 528 block partials.
__global__ __launch_bounds__(256) void finalize_kernel(const double* __restrict__ pblock,
                                                       float* __restrict__ out) {
    int b = blockIdx.x, t = threadIdx.x;
    const double* p = pblock + (size_t)b * PAIRS_PER_BATCH;
    double s = 0.0;
    for (int i = t; i < PAIRS_PER_BATCH; i += 256) s += p[i];
#pragma unroll
    for (int o = 32; o > 0; o >>= 1) s += __shfl_down(s, o);
    __shared__ double w[4];
    if ((t & 63) == 0) w[t >> 6] = s;
    __syncthreads();
    if (t == 0)
        out[b] = (float)((w[0] + w[1] + w[2] + w[3]) / ((double)N_HALF * (double)N_HALF));
}

extern "C" void kernel_launch(void* const* d_in, const int* in_sizes, int n_in,
                              void* d_out, int out_size, void* d_ws, size_t ws_size,
                              hipStream_t stream) {
    const float* x = (const float*)d_in[0];
    const float* y = (const float*)d_in[1];
    float* out = (float*)d_out;
    char* ws = (char*)d_ws;

    double* pblock      = (double*)ws;                    // 2112*8 = 16896 B
    float*  k0arr       = (float*)(ws + 16896);           // 16 B
    float*  ssq_part    = (float*)(ws + 20480);           // 1 KB
    float*  colsum_part = (float*)(ws + 24576);           // 64 KB
    float*  sq          = (float*)(ws + 98304);           // 64 KB
    unsigned short* tot_hi = (unsigned short*)(ws + 163840);            // 2 MB
    unsigned short* tot_lo = (unsigned short*)(ws + 163840 + 2097152);  // 2 MB

    // no memset needed: every ws word consumed is unconditionally written
    // earlier in the same call (no atomic accumulators).

    prep_kernel<<<256, 256, 0, stream>>>(x, y, tot_hi, tot_lo, sq, ssq_part, colsum_part);
    bw_kernel<<<1, 256, 0, stream>>>(ssq_part, colsum_part, k0arr);
    mmd_mfma<<<NWG, 256, 0, stream>>>(tot_hi, tot_lo, sq, k0arr, pblock);
    finalize_kernel<<<BATCH, 256, 0, stream>>>(pblock, out);
}